// Round 10
// baseline (282.659 us; speedup 1.0000x reference)
//
#include <hip/hip_runtime.h>
#include <hip/hip_bf16.h>

#define N_NODES 100000
#define N_EDGES 262144
#define IN_DIM 768
#define HIDDEN 256
#define BM 256
#define BK 32
#define NK (IN_DIM / BK)       // 24
#define M_BLOCKS 391           // ceil(100000/256)
#define M_PAD (M_BLOCKS * BM)  // 100096

typedef __attribute__((ext_vector_type(8))) short short8;
typedef __attribute__((ext_vector_type(4))) float f32x4;

__device__ __forceinline__ unsigned short f32_to_bf16(float f) {
    unsigned int u = __builtin_bit_cast(unsigned int, f);
    u = (u + 0x7FFFu + ((u >> 16) & 1u)) >> 16;
    return (unsigned short)u;
}
__device__ __forceinline__ float bf16_to_f32(unsigned short h) {
    unsigned int u = ((unsigned int)h) << 16;
    return __builtin_bit_cast(float, u);
}
__device__ __forceinline__ short8 cvt8(float4 lo, float4 hi) {
    short8 w;
    w[0] = (short)f32_to_bf16(lo.x); w[1] = (short)f32_to_bf16(lo.y);
    w[2] = (short)f32_to_bf16(lo.z); w[3] = (short)f32_to_bf16(lo.w);
    w[4] = (short)f32_to_bf16(hi.x); w[5] = (short)f32_to_bf16(hi.y);
    w[6] = (short)f32_to_bf16(hi.z); w[7] = (short)f32_to_bf16(hi.w);
    return w;
}

// Wt[g][n][k] = bf16(W1[g*768 + k][n]) ; k-contiguous for 16B staging loads
__global__ __launch_bounds__(256) void convert_w1(const float* __restrict__ W1,
                                                  unsigned short* __restrict__ Wt) {
    int t = blockIdx.x * blockDim.x + threadIdx.x;
    if (t >= 2 * HIDDEN * IN_DIM) return;
    int k = t % IN_DIM;
    int n = (t / IN_DIM) % HIDDEN;
    int g = t / (IN_DIM * HIDDEN);
    Wt[t] = f32_to_bf16(W1[(size_t)(g * IN_DIM + k) * HIDDEN + n]);
}

// P = bf16(X) @ bf16(W1half). BM=256 (halves B re-read traffic vs BM=128),
// BK=32, 8 waves, wave-tile 128m x 64n. R2-proven 2-barrier loop with
// 2-deep register prefetch banks; single-buffered 32KB LDS; swizzle
// granule ^= (row>>1)&3 (R5-measured 0 conflicts).
__global__ __launch_bounds__(512) void node_gemm(const float* __restrict__ X0,
                                                 const float* __restrict__ X1,
                                                 const unsigned short* __restrict__ WtAll,
                                                 unsigned short* __restrict__ Pout,
                                                 unsigned short* __restrict__ Qout) {
    const int g = blockIdx.y;
    const float* __restrict__ X = g ? X1 : X0;
    const unsigned short* __restrict__ Wt = WtAll + (size_t)g * IN_DIM * HIDDEN;
    unsigned short* __restrict__ Out = g ? Qout : Pout;

    __shared__ __attribute__((aligned(16))) char As[BM * BK * 2];     // 16 KB
    __shared__ __attribute__((aligned(16))) char Bs[HIDDEN * BK * 2]; // 16 KB

    const int m0   = blockIdx.x * BM;
    const int tid  = threadIdx.x;
    const int lane = tid & 63;
    const int wid  = tid >> 6;
    const int wm   = wid >> 2;  // 0..1 -> 128-row slab
    const int wn   = wid & 3;   // 0..3 -> 64-col slab
    const int lr   = lane & 15;
    const int c    = lane >> 4; // 0..3 (k-chunk)

    // staging: thread -> row sr (0..255), half sh (16 elems = 2 granules)
    const int sr = tid >> 1;
    const int sh = tid & 1;
    int arow = m0 + sr; if (arow >= N_NODES) arow = N_NODES - 1; // pad rows: copies
    const float*          aptr = X  + (size_t)arow * IN_DIM + sh * 16;
    const unsigned short* bptr = Wt + (size_t)sr   * IN_DIM + sh * 16;
    const int swz = (sr >> 1) & 3;
    char* const aw0 = As + sr * 64 + (((2 * sh)     ^ swz) << 4);
    char* const aw1 = As + sr * 64 + (((2 * sh + 1) ^ swz) << 4);
    char* const bw0 = Bs + sr * 64 + (((2 * sh)     ^ swz) << 4);
    char* const bw1 = Bs + sr * 64 + (((2 * sh + 1) ^ swz) << 4);

    f32x4 acc[8][4] = {};
    float4 Abk0[4], Abk1[4];
    short8 Bbk0[2], Bbk1[2];

#define LOADK(KT, AB, BB) do {                                    \
        const float* _p = aptr + (KT) * BK;                       \
        AB[0] = *(const float4*)(_p);                             \
        AB[1] = *(const float4*)(_p + 4);                         \
        AB[2] = *(const float4*)(_p + 8);                         \
        AB[3] = *(const float4*)(_p + 12);                        \
        const unsigned short* _q = bptr + (KT) * BK;              \
        BB[0] = *(const short8*)(_q);                             \
        BB[1] = *(const short8*)(_q + 8);                         \
    } while (0)

#define WRITEK(AB, BB) do {                                       \
        *(short8*)aw0 = cvt8(AB[0], AB[1]);                       \
        *(short8*)aw1 = cvt8(AB[2], AB[3]);                       \
        *(short8*)bw0 = BB[0];                                    \
        *(short8*)bw1 = BB[1];                                    \
    } while (0)

#define COMPUTE() do {                                            \
        short8 afr[8], bfr[4];                                    \
        _Pragma("unroll")                                         \
        for (int mi = 0; mi < 8; ++mi) {                          \
            int r = wm * 128 + mi * 16 + lr;                      \
            afr[mi] = *(const short8*)(As + r * 64 + ((c ^ ((r >> 1) & 3)) << 4)); \
        }                                                         \
        _Pragma("unroll")                                         \
        for (int ni = 0; ni < 4; ++ni) {                          \
            int n = wn * 64 + ni * 16 + lr;                       \
            bfr[ni] = *(const short8*)(Bs + n * 64 + ((c ^ ((n >> 1) & 3)) << 4)); \
        }                                                         \
        __builtin_amdgcn_s_setprio(1);                            \
        _Pragma("unroll")                                         \
        for (int mi = 0; mi < 8; ++mi)                            \
            _Pragma("unroll")                                     \
            for (int ni = 0; ni < 4; ++ni)                        \
                acc[mi][ni] = __builtin_amdgcn_mfma_f32_16x16x32_bf16( \
                    bfr[ni], afr[mi], acc[mi][ni], 0, 0, 0);      \
        __builtin_amdgcn_s_setprio(0);                            \
    } while (0)

    // prologue: tile0 -> bank0 -> LDS; tile1 -> bank1 (stays in regs)
    LOADK(0, Abk0, Bbk0);
    LOADK(1, Abk1, Bbk1);
    WRITEK(Abk0, Bbk0);
    __syncthreads();

    for (int ks2 = 0; ks2 < NK; ks2 += 2) {
        int ka = ks2 + 2; if (ka > NK - 1) ka = NK - 1;
        int kb = ks2 + 3; if (kb > NK - 1) kb = NK - 1;
        // step ks2 (LDS holds tile ks2)
        LOADK(ka, Abk0, Bbk0);      // issue early; consumer is 1.5 steps away
        COMPUTE();
        __syncthreads();            // all reads of tile ks2 done
        WRITEK(Abk1, Bbk1);         // tile ks2+1 (loaded a full step ago)
        __syncthreads();
        // step ks2+1
        LOADK(kb, Abk1, Bbk1);
        COMPUTE();
        __syncthreads();
        WRITEK(Abk0, Bbk0);         // tile ks2+2
        __syncthreads();
    }

    // store: m = m0 + wm*128 + mi*16 + lr, n = wn*64 + ni*16 + c*4 + reg
    const int mrow = wm * 128 + lr;
    const int nb0  = wn * 64 + (c << 2);
#pragma unroll
    for (int mi = 0; mi < 8; ++mi) {
        size_t mg = (size_t)(m0 + mrow + mi * 16);   // < M_PAD, pad rows benign
#pragma unroll
        for (int ni = 0; ni < 4; ++ni) {
            f32x4 a = acc[mi][ni];
            ushort4 w;
            w.x = f32_to_bf16(a[0]); w.y = f32_to_bf16(a[1]);
            w.z = f32_to_bf16(a[2]); w.w = f32_to_bf16(a[3]);
            *(ushort4*)(Out + mg * HIDDEN + nb0 + ni * 16) = w;
        }
    }
#undef LOADK
#undef WRITEK
#undef COMPUTE
}

// out[e] = relu(P[s]+Q[d]+b1) . W2 + b2 ; one wave per edge, lane j owns dims 4j..4j+3
__global__ __launch_bounds__(256) void edge_mlp(const unsigned short* __restrict__ P,
                                                const unsigned short* __restrict__ Q,
                                                const int* __restrict__ s_idx,
                                                const int* __restrict__ d_idx,
                                                const float* __restrict__ b1,
                                                const float* __restrict__ W2,
                                                const float* __restrict__ b2,
                                                float* __restrict__ out) {
    const int lane = threadIdx.x & 63;
    const int gw = (blockIdx.x * blockDim.x + threadIdx.x) >> 6;
    const int nw = (gridDim.x * blockDim.x) >> 6;
    const float4 b1v = *(const float4*)(b1 + lane * 4);
    const float4 w2v = *(const float4*)(W2 + lane * 4);
    const float b2s = *b2;
    for (int e = gw; e < N_EDGES; e += nw) {
        int s = s_idx[e];
        int d = d_idx[e];
        ushort4 pv = *(const ushort4*)(P + (size_t)s * HIDDEN + lane * 4);
        ushort4 qv = *(const ushort4*)(Q + (size_t)d * HIDDEN + lane * 4);
        float h, sum;
        h = bf16_to_f32(pv.x) + bf16_to_f32(qv.x) + b1v.x; h = fmaxf(h, 0.f); sum  = h * w2v.x;
        h = bf16_to_f32(pv.y) + bf16_to_f32(qv.y) + b1v.y; h = fmaxf(h, 0.f); sum += h * w2v.y;
        h = bf16_to_f32(pv.z) + bf16_to_f32(qv.z) + b1v.z; h = fmaxf(h, 0.f); sum += h * w2v.z;
        h = bf16_to_f32(pv.w) + bf16_to_f32(qv.w) + b1v.w; h = fmaxf(h, 0.f); sum += h * w2v.w;
#pragma unroll
        for (int off = 32; off; off >>= 1) sum += __shfl_xor(sum, off, 64);
        if (lane == 0) out[e] = sum + b2s;
    }
}

extern "C" void kernel_launch(void* const* d_in, const int* in_sizes, int n_in,
                              void* d_out, int out_size, void* d_ws, size_t ws_size,
                              hipStream_t stream) {
    const float* x_src = (const float*)d_in[0];
    const float* x_dst = (const float*)d_in[1];
    const int*   s_idx = (const int*)d_in[2];
    const int*   d_idx = (const int*)d_in[3];
    const float* W1    = (const float*)d_in[4];
    const float* b1    = (const float*)d_in[5];
    const float* W2    = (const float*)d_in[6];
    const float* b2    = (const float*)d_in[7];
    float* out = (float*)d_out;

    char* ws = (char*)d_ws;
    // layout: Wt (786432 B) | P (M_PAD*256*2 B) | Q (M_PAD*256*2 B) => ~103.3 MB
    unsigned short* Wt = (unsigned short*)ws;
    unsigned short* P  = (unsigned short*)(ws + 786432);
    unsigned short* Q  = (unsigned short*)(ws + 786432 + (size_t)M_PAD * HIDDEN * 2);

    convert_w1<<<(2 * IN_DIM * HIDDEN + 255) / 256, 256, 0, stream>>>(W1, Wt);

    dim3 gg(M_BLOCKS, 2);
    node_gemm<<<gg, 512, 0, stream>>>(x_src, x_dst, Wt, P, Q);

    edge_mlp<<<2048, 256, 0, stream>>>(P, Q, s_idx, d_idx, b1, W2, b2, out);
}